// Round 5
// baseline (735.288 us; speedup 1.0000x reference)
//
#include <hip/hip_runtime.h>

#define N_NODES 100000
#define N_EDGES 1600000
#define DIM 64
#define NLAYER 4
#define NGRAPH 128
#define BN_EPS 1e-5f
#define NSHARD 8

// ---------------- CSR build ----------------
// 8-way sharded histogram: same-line atomic serialization was the k_hist
// bottleneck (avg 256 atomics per 64B line); sharding by blockIdx&7 spreads
// the RMWs over 8x as many L2 lines. The atomic return value IS the rank
// within (dst, shard); k_sum8 turns shard counts into shard prefix offsets.

__global__ void k_hist(const int* __restrict__ ei, int* __restrict__ cnt8,
                       int* __restrict__ rank) {
    int e = blockIdx.x * blockDim.x + threadIdx.x;
    if (e < N_EDGES) {
        int d = ei[N_EDGES + e];
        int s = blockIdx.x & (NSHARD - 1);
        rank[e] = atomicAdd(&cnt8[s * N_NODES + d], 1);
    }
}

__global__ void k_sum8(int* __restrict__ cnt8, int* __restrict__ cnt) {
    int i = blockIdx.x * blockDim.x + threadIdx.x;
    if (i < N_NODES) {
        int run = 0;
#pragma unroll
        for (int s = 0; s < NSHARD; s++) {
            int c = cnt8[s * N_NODES + i];
            cnt8[s * N_NODES + i] = run;   // in-place: per-shard prefix offset
            run += c;
        }
        cnt[i] = run;
    }
}

__global__ void k_scan1(const int* __restrict__ cnt, int* __restrict__ exc,
                        int* __restrict__ bsums) {
    __shared__ int s[256];
    int i = blockIdx.x * 256 + threadIdx.x;
    int v = (i < N_NODES) ? cnt[i] : 0;
    s[threadIdx.x] = v;
    __syncthreads();
    for (int off = 1; off < 256; off <<= 1) {
        int t = (threadIdx.x >= off) ? s[threadIdx.x - off] : 0;
        __syncthreads();
        s[threadIdx.x] += t;
        __syncthreads();
    }
    if (i < N_NODES) exc[i] = s[threadIdx.x] - v;
    if (threadIdx.x == 255) bsums[blockIdx.x] = s[255];
}

__global__ void k_scan2(const int* __restrict__ bsums, int* __restrict__ boffs, int nb) {
    __shared__ int s[512];
    int v = ((int)threadIdx.x < nb) ? bsums[threadIdx.x] : 0;
    s[threadIdx.x] = v;
    __syncthreads();
    for (int off = 1; off < 512; off <<= 1) {
        int t = (threadIdx.x >= off) ? s[threadIdx.x - off] : 0;
        __syncthreads();
        s[threadIdx.x] += t;
        __syncthreads();
    }
    if ((int)threadIdx.x < nb) boffs[threadIdx.x] = s[threadIdx.x] - v;
}

__global__ void k_scan3(int* __restrict__ exc, const int* __restrict__ boffs) {
    int i = blockIdx.x * 256 + threadIdx.x;
    if (i < N_NODES) exc[i] += boffs[blockIdx.x];
}

__global__ void k_fill(const int* __restrict__ ei, const int* __restrict__ rowptr,
                       const int* __restrict__ cnt8, const int* __restrict__ rank,
                       int* __restrict__ csr) {
    int e = blockIdx.x * blockDim.x + threadIdx.x;
    if (e < N_EDGES) {
        int d = ei[N_EDGES + e];
        int s = blockIdx.x & (NSHARD - 1);
        csr[rowptr[d] + cnt8[s * N_NODES + d] + rank[e]] = ei[e];
    }
}

__global__ void k_prep(const int* __restrict__ cnt, const int* __restrict__ batch,
                       float* __restrict__ invdeg, float* __restrict__ invg) {
    int i = blockIdx.x * blockDim.x + threadIdx.x;
    if (i < N_NODES) invdeg[i] = 1.0f / (float)max(cnt[i], 1);
    if (i < NGRAPH) {
        int key = i, lo = 0, hi = N_NODES;
        while (lo < hi) { int m = (lo + hi) >> 1; if (batch[m] < key) lo = m + 1; else hi = m; }
        int a = lo;
        key = i + 1; lo = 0; hi = N_NODES;
        while (lo < hi) { int m = (lo + hi) >> 1; if (batch[m] < key) lo = m + 1; else hi = m; }
        invg[i] = 1.0f / (float)max(lo - a, 1);
    }
}

// ---------------- k_agg: t = h + mean_neighbors(h) ----------------
// Gather-only kernel at 8 waves/SIMD. 16 lanes cover one 64-float row via
// float4, so one dwordx4 gather pulls 4 edges (1 KB/instruction); two
// independent 4-edge groups in flight per loop iteration. Quarter-partials
// combined with shfl_xor(16/32).

__global__ __launch_bounds__(256, 8)
void k_agg(const float* __restrict__ h, const int* __restrict__ rowptr,
           const int* __restrict__ cnt, const int* __restrict__ csr,
           const float* __restrict__ invdeg, float* __restrict__ tout) {
    const int lane = threadIdx.x & 63;
    const int q = lane >> 4;    // edge slot within a 4-edge group
    const int p = lane & 15;    // float4 column group
    int wid_raw = (blockIdx.x << 2) | (threadIdx.x >> 6);
    const int wid = __builtin_amdgcn_readfirstlane(wid_raw);
    const int nwaves = gridDim.x << 2;

    for (int n = wid; n < N_NODES; n += nwaves) {
        const int start = rowptr[n];
        const int deg = cnt[n];
        const float idg = invdeg[n];
        float4 acc = make_float4(0.f, 0.f, 0.f, 0.f);
        for (int e = 0; e < deg; e += 8) {
            const int e0 = e + q;
            const int e1 = e + 4 + q;
            const int last = deg - 1;
            int i0 = csr[start + min(e0, last)];
            int i1 = csr[start + min(e1, last)];
            float m0 = (e0 < deg) ? 1.f : 0.f;
            float m1 = (e1 < deg) ? 1.f : 0.f;
            const float4 v0 = *(const float4*)(h + (size_t)i0 * 64 + p * 4);
            const float4 v1 = *(const float4*)(h + (size_t)i1 * 64 + p * 4);
            acc.x = fmaf(v0.x, m0, acc.x);
            acc.y = fmaf(v0.y, m0, acc.y);
            acc.z = fmaf(v0.z, m0, acc.z);
            acc.w = fmaf(v0.w, m0, acc.w);
            acc.x = fmaf(v1.x, m1, acc.x);
            acc.y = fmaf(v1.y, m1, acc.y);
            acc.z = fmaf(v1.z, m1, acc.z);
            acc.w = fmaf(v1.w, m1, acc.w);
        }
        // combine the 4 edge-slot partials (lanes differing in bits 4,5)
        acc.x += __shfl_xor(acc.x, 16, 64);
        acc.y += __shfl_xor(acc.y, 16, 64);
        acc.z += __shfl_xor(acc.z, 16, 64);
        acc.w += __shfl_xor(acc.w, 16, 64);
        acc.x += __shfl_xor(acc.x, 32, 64);
        acc.y += __shfl_xor(acc.y, 32, 64);
        acc.z += __shfl_xor(acc.z, 32, 64);
        acc.w += __shfl_xor(acc.w, 32, 64);

        const float4 self = *(const float4*)(h + (size_t)n * 64 + p * 4);
        float4 t;
        t.x = fmaf(acc.x, idg, self.x);
        t.y = fmaf(acc.y, idg, self.y);
        t.z = fmaf(acc.z, idg, self.z);
        t.w = fmaf(acc.w, idg, self.w);
        if (q == 0) *(float4*)(tout + (size_t)n * 64 + p * 4) = t;
    }
}

// ---------------- k_mlp1: z = t@W1 + b1 (in place) + BN moments ----------------
// Pure streaming: 4 nodes per iteration give 4 independent readlane-FMA chains.

#define CHUNK_M 28  // multiple of 4; N % 4 == 0 so every wave sees full quads

__global__ __launch_bounds__(256, 4)
void k_mlp1(float* __restrict__ t, const float* __restrict__ W1,
            const float* __restrict__ b1,
            float* __restrict__ colsum, float* __restrict__ colsumsq) {
    const int lane = threadIdx.x & 63;
    int wid_raw = (blockIdx.x << 2) | (threadIdx.x >> 6);
    const int wid = __builtin_amdgcn_readfirstlane(wid_raw);
    const int n0 = wid * CHUNK_M;
    const int n1 = min(N_NODES, n0 + CHUNK_M);

    float w[64];
#pragma unroll
    for (int k = 0; k < 64; k++) w[k] = W1[k * 64 + lane];
#pragma unroll
    for (int k = 0; k < 64; k++) asm("" : "+v"(w[k]));
    const float bj = b1[lane];

    float ls = 0.f, lq = 0.f;
    for (int n = n0; n + 4 <= n1; n += 4) {
        float ta = t[(size_t)n * 64 + lane];
        float tb = t[(size_t)(n + 1) * 64 + lane];
        float tc = t[(size_t)(n + 2) * 64 + lane];
        float td = t[(size_t)(n + 3) * 64 + lane];
        float za = bj, zb = bj, zc = bj, zd = bj;
#pragma unroll
        for (int k = 0; k < 64; k++) {
            float ka = __int_as_float(__builtin_amdgcn_readlane(__float_as_int(ta), k));
            float kb = __int_as_float(__builtin_amdgcn_readlane(__float_as_int(tb), k));
            float kc = __int_as_float(__builtin_amdgcn_readlane(__float_as_int(tc), k));
            float kd = __int_as_float(__builtin_amdgcn_readlane(__float_as_int(td), k));
            za = fmaf(ka, w[k], za);
            zb = fmaf(kb, w[k], zb);
            zc = fmaf(kc, w[k], zc);
            zd = fmaf(kd, w[k], zd);
        }
        t[(size_t)n * 64 + lane] = za;
        t[(size_t)(n + 1) * 64 + lane] = zb;
        t[(size_t)(n + 2) * 64 + lane] = zc;
        t[(size_t)(n + 3) * 64 + lane] = zd;
        ls += (za + zb) + (zc + zd);
        lq += (za * za + zb * zb) + (zc * zc + zd * zd);
    }

    __shared__ float rs[256], rq[256];
    rs[threadIdx.x] = ls;
    rq[threadIdx.x] = lq;
    __syncthreads();
    if (threadIdx.x < 64) {
        float a = rs[threadIdx.x] + rs[threadIdx.x + 64] + rs[threadIdx.x + 128] + rs[threadIdx.x + 192];
        float b = rq[threadIdx.x] + rq[threadIdx.x + 64] + rq[threadIdx.x + 128] + rq[threadIdx.x + 192];
        atomicAdd(&colsum[threadIdx.x], a);
        atomicAdd(&colsumsq[threadIdx.x], b);
    }
}

// ---------------- BN prep ----------------

__global__ void k_bnprep(float* __restrict__ colsum, float* __restrict__ colsumsq,
                         const float* __restrict__ gamma, const float* __restrict__ beta,
                         float* __restrict__ scale, float* __restrict__ shift) {
    int j = threadIdx.x;  // 64 threads
    float invn = 1.0f / (float)N_NODES;
    float mu = colsum[j] * invn;
    float var = colsumsq[j] * invn - mu * mu;
    float rsg = rsqrtf(var + BN_EPS);
    float sc = gamma[j] * rsg;
    scale[j] = sc;
    shift[j] = beta[j] - mu * sc;
    colsum[j] = 0.f;
    colsumsq[j] = 0.f;
}

// ---------------- k_mlp2: h = relu(bn(z))@W2 + b2, pools ----------------

__global__ __launch_bounds__(256, 4)
void k_mlp2(const float* __restrict__ z, const float* __restrict__ W2,
            const float* __restrict__ b2, const float* __restrict__ scale,
            const float* __restrict__ shift, const int* __restrict__ batch,
            float* __restrict__ hout, float* __restrict__ node_pool,
            float* __restrict__ gacc, int first) {
    const int lane = threadIdx.x & 63;
    int wid_raw = (blockIdx.x << 2) | (threadIdx.x >> 6);
    const int wid = __builtin_amdgcn_readfirstlane(wid_raw);
    const int n0 = wid * CHUNK_M;
    const int n1 = min(N_NODES, n0 + CHUNK_M);

    float w[64];
#pragma unroll
    for (int k = 0; k < 64; k++) w[k] = W2[k * 64 + lane];
#pragma unroll
    for (int k = 0; k < 64; k++) asm("" : "+v"(w[k]));
    const float bj = b2[lane], sc = scale[lane], sh = shift[lane];

    int curg = -1;
    float ga = 0.f;
    for (int n = n0; n + 4 <= n1; n += 4) {
        float ra = fmaxf(fmaf(z[(size_t)n * 64 + lane], sc, sh), 0.f);
        float rb = fmaxf(fmaf(z[(size_t)(n + 1) * 64 + lane], sc, sh), 0.f);
        float rc = fmaxf(fmaf(z[(size_t)(n + 2) * 64 + lane], sc, sh), 0.f);
        float rd = fmaxf(fmaf(z[(size_t)(n + 3) * 64 + lane], sc, sh), 0.f);
        float ha = bj, hb = bj, hc = bj, hd = bj;
#pragma unroll
        for (int k = 0; k < 64; k++) {
            float ka = __int_as_float(__builtin_amdgcn_readlane(__float_as_int(ra), k));
            float kb = __int_as_float(__builtin_amdgcn_readlane(__float_as_int(rb), k));
            float kc = __int_as_float(__builtin_amdgcn_readlane(__float_as_int(rc), k));
            float kd = __int_as_float(__builtin_amdgcn_readlane(__float_as_int(rd), k));
            ha = fmaf(ka, w[k], ha);
            hb = fmaf(kb, w[k], hb);
            hc = fmaf(kc, w[k], hc);
            hd = fmaf(kd, w[k], hd);
        }
        hout[(size_t)n * 64 + lane] = ha;
        hout[(size_t)(n + 1) * 64 + lane] = hb;
        hout[(size_t)(n + 2) * 64 + lane] = hc;
        hout[(size_t)(n + 3) * 64 + lane] = hd;
        if (first) {
            node_pool[(size_t)n * 64 + lane] = ha;
            node_pool[(size_t)(n + 1) * 64 + lane] = hb;
            node_pool[(size_t)(n + 2) * 64 + lane] = hc;
            node_pool[(size_t)(n + 3) * 64 + lane] = hd;
        } else {
            node_pool[(size_t)n * 64 + lane] += ha;
            node_pool[(size_t)(n + 1) * 64 + lane] += hb;
            node_pool[(size_t)(n + 2) * 64 + lane] += hc;
            node_pool[(size_t)(n + 3) * 64 + lane] += hd;
        }
        float hv[4] = {ha, hb, hc, hd};
#pragma unroll
        for (int j = 0; j < 4; j++) {
            int g = batch[n + j];
            if (g != curg) {
                if (curg >= 0) atomicAdd(&gacc[curg * 64 + lane], ga);
                ga = 0.f;
                curg = g;
            }
            ga += hv[j];
        }
    }
    if (curg >= 0) atomicAdd(&gacc[curg * 64 + lane], ga);
}

__global__ void k_gfinal(const float* __restrict__ gacc, const float* __restrict__ invg,
                         float* __restrict__ gout) {
    int i = blockIdx.x * blockDim.x + threadIdx.x;
    if (i < NGRAPH * 64) gout[i] = gacc[i] * invg[i >> 6];
}

// ---------------- launch ----------------

extern "C" void kernel_launch(void* const* d_in, const int* in_sizes, int n_in,
                              void* d_out, int out_size, void* d_ws, size_t ws_size,
                              hipStream_t stream) {
    (void)in_sizes; (void)n_in; (void)out_size; (void)ws_size;
    const float* x     = (const float*)d_in[0];
    const int*   ei    = (const int*)d_in[1];
    const int*   batch = (const int*)d_in[2];
    const float* W1    = (const float*)d_in[3];
    const float* b1    = (const float*)d_in[4];
    const float* gamma = (const float*)d_in[5];
    const float* beta  = (const float*)d_in[6];
    const float* W2    = (const float*)d_in[7];
    const float* b2    = (const float*)d_in[8];
    float* out = (float*)d_out;  // [N*64] node_pool, then [G*64] g_pool

    size_t o = 0;
    size_t o_cnt8    = o; o += (size_t)NSHARD * N_NODES;
    size_t o_colsum  = o; o += 64;
    size_t o_colsq   = o; o += 64;
    size_t o_gacc    = o; o += (size_t)NGRAPH * 64;
    size_t zero_elems = o;
    size_t o_cnt     = o; o += N_NODES;
    size_t o_rowptr  = o; o += N_NODES;
    size_t o_bsums   = o; o += 512;
    size_t o_boffs   = o; o += 512;
    size_t o_invdeg  = o; o += N_NODES;
    size_t o_invg    = o; o += NGRAPH;
    size_t o_scale   = o; o += 64;
    size_t o_shift   = o; o += 64;
    size_t o_rank    = o; o += N_EDGES;
    size_t o_csr     = o; o += N_EDGES;
    size_t o_bufA    = o; o += (size_t)N_NODES * 64;
    size_t o_bufB    = o; o += (size_t)N_NODES * 64;

    int*   wsi = (int*)d_ws;
    float* wsf = (float*)d_ws;
    int*   cnt8   = wsi + o_cnt8;
    float* colsum = wsf + o_colsum;
    float* colsq  = wsf + o_colsq;
    float* gacc   = wsf + o_gacc;
    int*   cnt    = wsi + o_cnt;
    int*   rowptr = wsi + o_rowptr;
    int*   bsums  = wsi + o_bsums;
    int*   boffs  = wsi + o_boffs;
    float* invdeg = wsf + o_invdeg;
    float* invg   = wsf + o_invg;
    float* scale  = wsf + o_scale;
    float* shift  = wsf + o_shift;
    int*   rank   = wsi + o_rank;
    int*   csr    = wsi + o_csr;
    float* bufA   = wsf + o_bufA;
    float* bufB   = wsf + o_bufB;

    hipMemsetAsync(d_ws, 0, zero_elems * 4, stream);

    const int eb = (N_EDGES + 255) / 256;
    const int nb = (N_NODES + 255) / 256;  // 391 <= 512

    k_hist<<<eb, 256, 0, stream>>>(ei, cnt8, rank);
    k_sum8<<<nb, 256, 0, stream>>>(cnt8, cnt);
    k_scan1<<<nb, 256, 0, stream>>>(cnt, rowptr, bsums);
    k_scan2<<<1, 512, 0, stream>>>(bsums, boffs, nb);
    k_scan3<<<nb, 256, 0, stream>>>(rowptr, boffs);
    k_prep<<<nb, 256, 0, stream>>>(cnt, batch, invdeg, invg);
    k_fill<<<eb, 256, 0, stream>>>(ei, rowptr, cnt8, rank, csr);

    const int gridAgg = 2048;                                    // 8 blocks/CU
    const int gridM = (N_NODES + CHUNK_M * 4 - 1) / (CHUNK_M * 4);  // 893
    for (int l = 0; l < NLAYER; l++) {
        const float* h_in = (l == 0) ? x : bufB;
        k_agg<<<gridAgg, 256, 0, stream>>>(h_in, rowptr, cnt, csr, invdeg, bufA);
        k_mlp1<<<gridM, 256, 0, stream>>>(bufA, W1 + l * 4096, b1 + l * 64,
                                          colsum, colsq);
        k_bnprep<<<1, 64, 0, stream>>>(colsum, colsq, gamma + l * 64, beta + l * 64,
                                       scale, shift);
        k_mlp2<<<gridM, 256, 0, stream>>>(bufA, W2 + l * 4096, b2 + l * 64,
                                          scale, shift, batch,
                                          bufB, out, gacc, (l == 0) ? 1 : 0);
    }
    k_gfinal<<<32, 256, 0, stream>>>(gacc, invg, out + (size_t)N_NODES * 64);
}

// Round 6
// 685.962 us; speedup vs baseline: 1.0719x; 1.0719x over previous
//
#include <hip/hip_runtime.h>

#define N_NODES 100000
#define N_EDGES 1600000
#define DIM 64
#define NLAYER 4
#define NGRAPH 128
#define BN_EPS 1e-5f
#define NSHARD 16

// ---------------- CSR build ----------------
// 16-way sharded histogram: spreads same-line atomic RMWs over 16x the L2
// lines. The atomic return IS the rank within (dst, shard); k_sumsh converts
// shard counts to per-shard prefix offsets so k_fill needs no atomics.

__global__ void k_hist(const int* __restrict__ ei, int* __restrict__ cntS,
                       int* __restrict__ rank) {
    int e = blockIdx.x * blockDim.x + threadIdx.x;
    if (e < N_EDGES) {
        int d = ei[N_EDGES + e];
        int s = blockIdx.x & (NSHARD - 1);
        rank[e] = atomicAdd(&cntS[s * N_NODES + d], 1);
    }
}

__global__ void k_sumsh(int* __restrict__ cntS, int* __restrict__ cnt) {
    int i = blockIdx.x * blockDim.x + threadIdx.x;
    if (i < N_NODES) {
        int run = 0;
#pragma unroll
        for (int s = 0; s < NSHARD; s++) {
            int c = cntS[s * N_NODES + i];
            cntS[s * N_NODES + i] = run;   // in-place: per-shard prefix offset
            run += c;
        }
        cnt[i] = run;
    }
}

__global__ void k_scan1(const int* __restrict__ cnt, int* __restrict__ exc,
                        int* __restrict__ bsums) {
    __shared__ int s[256];
    int i = blockIdx.x * 256 + threadIdx.x;
    int v = (i < N_NODES) ? cnt[i] : 0;
    s[threadIdx.x] = v;
    __syncthreads();
    for (int off = 1; off < 256; off <<= 1) {
        int t = (threadIdx.x >= off) ? s[threadIdx.x - off] : 0;
        __syncthreads();
        s[threadIdx.x] += t;
        __syncthreads();
    }
    if (i < N_NODES) exc[i] = s[threadIdx.x] - v;
    if (threadIdx.x == 255) bsums[blockIdx.x] = s[255];
}

__global__ void k_scan2(const int* __restrict__ bsums, int* __restrict__ boffs, int nb) {
    __shared__ int s[512];
    int v = ((int)threadIdx.x < nb) ? bsums[threadIdx.x] : 0;
    s[threadIdx.x] = v;
    __syncthreads();
    for (int off = 1; off < 512; off <<= 1) {
        int t = (threadIdx.x >= off) ? s[threadIdx.x - off] : 0;
        __syncthreads();
        s[threadIdx.x] += t;
        __syncthreads();
    }
    if ((int)threadIdx.x < nb) boffs[threadIdx.x] = s[threadIdx.x] - v;
}

__global__ void k_scan3(int* __restrict__ exc, const int* __restrict__ boffs) {
    int i = blockIdx.x * 256 + threadIdx.x;
    if (i < N_NODES) exc[i] += boffs[blockIdx.x];
}

__global__ void k_fill(const int* __restrict__ ei, const int* __restrict__ rowptr,
                       const int* __restrict__ cntS, const int* __restrict__ rank,
                       int* __restrict__ csr) {
    int e = blockIdx.x * blockDim.x + threadIdx.x;
    if (e < N_EDGES) {
        int d = ei[N_EDGES + e];
        int s = blockIdx.x & (NSHARD - 1);
        csr[rowptr[d] + cntS[s * N_NODES + d] + rank[e]] = ei[e];
    }
}

__global__ void k_prep(const int* __restrict__ cnt, const int* __restrict__ batch,
                       float* __restrict__ invdeg, float* __restrict__ invg) {
    int i = blockIdx.x * blockDim.x + threadIdx.x;
    if (i < N_NODES) invdeg[i] = 1.0f / (float)max(cnt[i], 1);
    if (i < NGRAPH) {
        int key = i, lo = 0, hi = N_NODES;
        while (lo < hi) { int m = (lo + hi) >> 1; if (batch[m] < key) lo = m + 1; else hi = m; }
        int a = lo;
        key = i + 1; lo = 0; hi = N_NODES;
        while (lo < hi) { int m = (lo + hi) >> 1; if (batch[m] < key) lo = m + 1; else hi = m; }
        invg[i] = 1.0f / (float)max(lo - a, 1);
    }
}

// One masked group of 8 edges for one node, 16-lane float4 layout:
// lane = (q,p), q=lane>>4 edge slot, p=lane&15 float4 column group.
// 2 idx loads + 2 dwordx4 gathers; mask handles the ragged tail.
__device__ __forceinline__ void grp8(const float* __restrict__ h,
                                     const int* __restrict__ cp,
                                     int e, int deg, int q, int p,
                                     float4& acc) {
    const int last = deg - 1;
    const int e0 = e + q;
    const int e1 = e + 4 + q;
    int i0 = cp[min(e0, last)];
    int i1 = cp[min(e1, last)];
    float m0 = (e0 < deg) ? 1.f : 0.f;
    float m1 = (e1 < deg) ? 1.f : 0.f;
    const float4 v0 = *(const float4*)(h + (size_t)i0 * 64 + p * 4);
    const float4 v1 = *(const float4*)(h + (size_t)i1 * 64 + p * 4);
    acc.x = fmaf(v0.x, m0, acc.x);
    acc.y = fmaf(v0.y, m0, acc.y);
    acc.z = fmaf(v0.z, m0, acc.z);
    acc.w = fmaf(v0.w, m0, acc.w);
    acc.x = fmaf(v1.x, m1, acc.x);
    acc.y = fmaf(v1.y, m1, acc.y);
    acc.z = fmaf(v1.z, m1, acc.z);
    acc.w = fmaf(v1.w, m1, acc.w);
}

// ---------------- Layer pass A: aggregate + GEMV(W1) + BN moments ----------------
// Fused (gather latency overlaps GEMV VALU across waves). Two nodes per
// iteration; float4 gathers (1 KB / instruction, 4x fewer VMEM ops than
// per-lane-scalar); w[64] register-resident for the readlane GEMV.

#define CHUNK_A 14  // even: pair loop covers every wave's range exactly

__global__ __launch_bounds__(256, 4)
void k_passA(const float* __restrict__ h, const float* __restrict__ W1,
             const float* __restrict__ b1,
             const int* __restrict__ rowptr, const int* __restrict__ cnt,
             const int* __restrict__ csr, const float* __restrict__ invdeg,
             float* __restrict__ z, float* __restrict__ colsum,
             float* __restrict__ colsumsq) {
    const int lane = threadIdx.x & 63;
    const int q = lane >> 4;
    const int p = lane & 15;
    int wid_raw = (blockIdx.x << 2) | (threadIdx.x >> 6);
    const int wid = __builtin_amdgcn_readfirstlane(wid_raw);
    const int n0 = wid * CHUNK_A;
    const int n1 = min(N_NODES, n0 + CHUNK_A);

    float w[64];
#pragma unroll
    for (int k = 0; k < 64; k++) w[k] = W1[k * 64 + lane];
#pragma unroll
    for (int k = 0; k < 64; k++) asm("" : "+v"(w[k]));   // keep register-resident
    const float bj = b1[lane];

    float ls = 0.f, lq = 0.f;
    for (int n = n0; n + 2 <= n1; n += 2) {
        const int sa = rowptr[n],     da = cnt[n];
        const int sb = rowptr[n + 1], db = cnt[n + 1];
        const float idga = invdeg[n], idgb = invdeg[n + 1];
        const int* __restrict__ ca = csr + sa;
        const int* __restrict__ cb = csr + sb;
        const float4 selfa = *(const float4*)(h + (size_t)n * 64 + p * 4);
        const float4 selfb = *(const float4*)(h + (size_t)(n + 1) * 64 + p * 4);

        float4 aa = make_float4(0.f, 0.f, 0.f, 0.f);
        float4 ab = make_float4(0.f, 0.f, 0.f, 0.f);
        const int m = min(da, db);
        int e = 0;
        for (; e < m; e += 8) {            // dual independent gather streams
            grp8(h, ca, e, da, q, p, aa);
            grp8(h, cb, e, db, q, p, ab);
        }
        for (; e < da; e += 8) grp8(h, ca, e, da, q, p, aa);
        for (; e < db; e += 8) grp8(h, cb, e, db, q, p, ab);

        // combine 4 edge-slot partials (lanes differing in bits 4,5)
        aa.x += __shfl_xor(aa.x, 16, 64); aa.y += __shfl_xor(aa.y, 16, 64);
        aa.z += __shfl_xor(aa.z, 16, 64); aa.w += __shfl_xor(aa.w, 16, 64);
        aa.x += __shfl_xor(aa.x, 32, 64); aa.y += __shfl_xor(aa.y, 32, 64);
        aa.z += __shfl_xor(aa.z, 32, 64); aa.w += __shfl_xor(aa.w, 32, 64);
        ab.x += __shfl_xor(ab.x, 16, 64); ab.y += __shfl_xor(ab.y, 16, 64);
        ab.z += __shfl_xor(ab.z, 16, 64); ab.w += __shfl_xor(ab.w, 16, 64);
        ab.x += __shfl_xor(ab.x, 32, 64); ab.y += __shfl_xor(ab.y, 32, 64);
        ab.z += __shfl_xor(ab.z, 32, 64); ab.w += __shfl_xor(ab.w, 32, 64);

        float4 ta, tb;
        ta.x = fmaf(aa.x, idga, selfa.x); ta.y = fmaf(aa.y, idga, selfa.y);
        ta.z = fmaf(aa.z, idga, selfa.z); ta.w = fmaf(aa.w, idga, selfa.w);
        tb.x = fmaf(ab.x, idgb, selfb.x); tb.y = fmaf(ab.y, idgb, selfb.y);
        tb.z = fmaf(ab.z, idgb, selfb.z); tb.w = fmaf(ab.w, idgb, selfb.w);

        // GEMV: t[k] lives in lane (k>>2), component (k&3); dual chains
        float za = bj, zb = bj;
#pragma unroll
        for (int p16 = 0; p16 < 16; p16++) {
            float a0 = __int_as_float(__builtin_amdgcn_readlane(__float_as_int(ta.x), p16));
            float a1 = __int_as_float(__builtin_amdgcn_readlane(__float_as_int(ta.y), p16));
            float a2 = __int_as_float(__builtin_amdgcn_readlane(__float_as_int(ta.z), p16));
            float a3 = __int_as_float(__builtin_amdgcn_readlane(__float_as_int(ta.w), p16));
            float b0 = __int_as_float(__builtin_amdgcn_readlane(__float_as_int(tb.x), p16));
            float b1v = __int_as_float(__builtin_amdgcn_readlane(__float_as_int(tb.y), p16));
            float b2v = __int_as_float(__builtin_amdgcn_readlane(__float_as_int(tb.z), p16));
            float b3 = __int_as_float(__builtin_amdgcn_readlane(__float_as_int(tb.w), p16));
            za = fmaf(a0, w[4 * p16 + 0], za);
            zb = fmaf(b0, w[4 * p16 + 0], zb);
            za = fmaf(a1, w[4 * p16 + 1], za);
            zb = fmaf(b1v, w[4 * p16 + 1], zb);
            za = fmaf(a2, w[4 * p16 + 2], za);
            zb = fmaf(b2v, w[4 * p16 + 2], zb);
            za = fmaf(a3, w[4 * p16 + 3], za);
            zb = fmaf(b3, w[4 * p16 + 3], zb);
        }
        z[(size_t)n * 64 + lane] = za;
        z[(size_t)(n + 1) * 64 + lane] = zb;
        ls += za + zb;
        lq += za * za + zb * zb;
    }

    __shared__ float rs[256], rq[256];
    rs[threadIdx.x] = ls;
    rq[threadIdx.x] = lq;
    __syncthreads();
    if (threadIdx.x < 64) {
        float a = rs[threadIdx.x] + rs[threadIdx.x + 64] + rs[threadIdx.x + 128] + rs[threadIdx.x + 192];
        float b = rq[threadIdx.x] + rq[threadIdx.x + 64] + rq[threadIdx.x + 128] + rq[threadIdx.x + 192];
        atomicAdd(&colsum[threadIdx.x], a);
        atomicAdd(&colsumsq[threadIdx.x], b);
    }
}

// ---------------- BN prep ----------------

__global__ void k_bnprep(float* __restrict__ colsum, float* __restrict__ colsumsq,
                         const float* __restrict__ gamma, const float* __restrict__ beta,
                         float* __restrict__ scale, float* __restrict__ shift) {
    int j = threadIdx.x;  // 64 threads
    float invn = 1.0f / (float)N_NODES;
    float mu = colsum[j] * invn;
    float var = colsumsq[j] * invn - mu * mu;
    float rsg = rsqrtf(var + BN_EPS);
    float sc = gamma[j] * rsg;
    scale[j] = sc;
    shift[j] = beta[j] - mu * sc;
    colsum[j] = 0.f;
    colsumsq[j] = 0.f;
}

// ---------------- Layer pass B: BN + ReLU + GEMV(W2) + pools ----------------

#define CHUNK_M 28  // multiple of 4

__global__ __launch_bounds__(256, 4)
void k_passB(const float* __restrict__ z, const float* __restrict__ W2,
             const float* __restrict__ b2, const float* __restrict__ scale,
             const float* __restrict__ shift, const int* __restrict__ batch,
             float* __restrict__ hout, float* __restrict__ node_pool,
             float* __restrict__ gacc, int first) {
    const int lane = threadIdx.x & 63;
    int wid_raw = (blockIdx.x << 2) | (threadIdx.x >> 6);
    const int wid = __builtin_amdgcn_readfirstlane(wid_raw);
    const int n0 = wid * CHUNK_M;
    const int n1 = min(N_NODES, n0 + CHUNK_M);

    float w[64];
#pragma unroll
    for (int k = 0; k < 64; k++) w[k] = W2[k * 64 + lane];
#pragma unroll
    for (int k = 0; k < 64; k++) asm("" : "+v"(w[k]));
    const float bj = b2[lane], sc = scale[lane], sh = shift[lane];

    int curg = -1;
    float ga = 0.f;
    for (int n = n0; n + 4 <= n1; n += 4) {
        float ra = fmaxf(fmaf(z[(size_t)n * 64 + lane], sc, sh), 0.f);
        float rb = fmaxf(fmaf(z[(size_t)(n + 1) * 64 + lane], sc, sh), 0.f);
        float rc = fmaxf(fmaf(z[(size_t)(n + 2) * 64 + lane], sc, sh), 0.f);
        float rd = fmaxf(fmaf(z[(size_t)(n + 3) * 64 + lane], sc, sh), 0.f);
        float ha = bj, hb = bj, hc = bj, hd = bj;
#pragma unroll
        for (int k = 0; k < 64; k++) {
            float ka = __int_as_float(__builtin_amdgcn_readlane(__float_as_int(ra), k));
            float kb = __int_as_float(__builtin_amdgcn_readlane(__float_as_int(rb), k));
            float kc = __int_as_float(__builtin_amdgcn_readlane(__float_as_int(rc), k));
            float kd = __int_as_float(__builtin_amdgcn_readlane(__float_as_int(rd), k));
            ha = fmaf(ka, w[k], ha);
            hb = fmaf(kb, w[k], hb);
            hc = fmaf(kc, w[k], hc);
            hd = fmaf(kd, w[k], hd);
        }
        hout[(size_t)n * 64 + lane] = ha;
        hout[(size_t)(n + 1) * 64 + lane] = hb;
        hout[(size_t)(n + 2) * 64 + lane] = hc;
        hout[(size_t)(n + 3) * 64 + lane] = hd;
        if (first) {
            node_pool[(size_t)n * 64 + lane] = ha;
            node_pool[(size_t)(n + 1) * 64 + lane] = hb;
            node_pool[(size_t)(n + 2) * 64 + lane] = hc;
            node_pool[(size_t)(n + 3) * 64 + lane] = hd;
        } else {
            node_pool[(size_t)n * 64 + lane] += ha;
            node_pool[(size_t)(n + 1) * 64 + lane] += hb;
            node_pool[(size_t)(n + 2) * 64 + lane] += hc;
            node_pool[(size_t)(n + 3) * 64 + lane] += hd;
        }
        float hv[4] = {ha, hb, hc, hd};
#pragma unroll
        for (int j = 0; j < 4; j++) {
            int g = batch[n + j];
            if (g != curg) {
                if (curg >= 0) atomicAdd(&gacc[curg * 64 + lane], ga);
                ga = 0.f;
                curg = g;
            }
            ga += hv[j];
        }
    }
    if (curg >= 0) atomicAdd(&gacc[curg * 64 + lane], ga);
}

__global__ void k_gfinal(const float* __restrict__ gacc, const float* __restrict__ invg,
                         float* __restrict__ gout) {
    int i = blockIdx.x * blockDim.x + threadIdx.x;
    if (i < NGRAPH * 64) gout[i] = gacc[i] * invg[i >> 6];
}

// ---------------- launch ----------------

extern "C" void kernel_launch(void* const* d_in, const int* in_sizes, int n_in,
                              void* d_out, int out_size, void* d_ws, size_t ws_size,
                              hipStream_t stream) {
    (void)in_sizes; (void)n_in; (void)out_size; (void)ws_size;
    const float* x     = (const float*)d_in[0];
    const int*   ei    = (const int*)d_in[1];
    const int*   batch = (const int*)d_in[2];
    const float* W1    = (const float*)d_in[3];
    const float* b1    = (const float*)d_in[4];
    const float* gamma = (const float*)d_in[5];
    const float* beta  = (const float*)d_in[6];
    const float* W2    = (const float*)d_in[7];
    const float* b2    = (const float*)d_in[8];
    float* out = (float*)d_out;  // [N*64] node_pool, then [G*64] g_pool

    size_t o = 0;
    size_t o_cntS    = o; o += (size_t)NSHARD * N_NODES;
    size_t o_colsum  = o; o += 64;
    size_t o_colsq   = o; o += 64;
    size_t o_gacc    = o; o += (size_t)NGRAPH * 64;
    size_t zero_elems = o;
    size_t o_cnt     = o; o += N_NODES;
    size_t o_rowptr  = o; o += N_NODES;
    size_t o_bsums   = o; o += 512;
    size_t o_boffs   = o; o += 512;
    size_t o_invdeg  = o; o += N_NODES;
    size_t o_invg    = o; o += NGRAPH;
    size_t o_scale   = o; o += 64;
    size_t o_shift   = o; o += 64;
    size_t o_rank    = o; o += N_EDGES;
    size_t o_csr     = o; o += N_EDGES;
    size_t o_bufA    = o; o += (size_t)N_NODES * 64;
    size_t o_bufB    = o; o += (size_t)N_NODES * 64;

    int*   wsi = (int*)d_ws;
    float* wsf = (float*)d_ws;
    int*   cntS   = wsi + o_cntS;
    float* colsum = wsf + o_colsum;
    float* colsq  = wsf + o_colsq;
    float* gacc   = wsf + o_gacc;
    int*   cnt    = wsi + o_cnt;
    int*   rowptr = wsi + o_rowptr;
    int*   bsums  = wsi + o_bsums;
    int*   boffs  = wsi + o_boffs;
    float* invdeg = wsf + o_invdeg;
    float* invg   = wsf + o_invg;
    float* scale  = wsf + o_scale;
    float* shift  = wsf + o_shift;
    int*   rank   = wsi + o_rank;
    int*   csr    = wsi + o_csr;
    float* bufA   = wsf + o_bufA;
    float* bufB   = wsf + o_bufB;

    hipMemsetAsync(d_ws, 0, zero_elems * 4, stream);

    const int eb = (N_EDGES + 255) / 256;
    const int nb = (N_NODES + 255) / 256;  // 391 <= 512

    k_hist<<<eb, 256, 0, stream>>>(ei, cntS, rank);
    k_sumsh<<<nb, 256, 0, stream>>>(cntS, cnt);
    k_scan1<<<nb, 256, 0, stream>>>(cnt, rowptr, bsums);
    k_scan2<<<1, 512, 0, stream>>>(bsums, boffs, nb);
    k_scan3<<<nb, 256, 0, stream>>>(rowptr, boffs);
    k_prep<<<nb, 256, 0, stream>>>(cnt, batch, invdeg, invg);
    k_fill<<<eb, 256, 0, stream>>>(ei, rowptr, cntS, rank, csr);

    const int gridA = (N_NODES + CHUNK_A * 4 - 1) / (CHUNK_A * 4);     // 1786
    const int gridM = (N_NODES + CHUNK_M * 4 - 1) / (CHUNK_M * 4);     // 893
    for (int l = 0; l < NLAYER; l++) {
        const float* h_in = (l == 0) ? x : bufB;
        k_passA<<<gridA, 256, 0, stream>>>(h_in, W1 + l * 4096, b1 + l * 64,
                                           rowptr, cnt, csr, invdeg,
                                           bufA, colsum, colsq);
        k_bnprep<<<1, 64, 0, stream>>>(colsum, colsq, gamma + l * 64, beta + l * 64,
                                       scale, shift);
        k_passB<<<gridM, 256, 0, stream>>>(bufA, W2 + l * 4096, b2 + l * 64,
                                           scale, shift, batch,
                                           bufB, out, gacc, (l == 0) ? 1 : 0);
    }
    k_gfinal<<<32, 256, 0, stream>>>(gacc, invg, out + (size_t)N_NODES * 64);
}

// Round 7
// 669.070 us; speedup vs baseline: 1.0990x; 1.0252x over previous
//
#include <hip/hip_runtime.h>

#define N_NODES 100000
#define N_EDGES 1600000
#define DIM 64
#define NLAYER 4
#define NGRAPH 128
#define BN_EPS 1e-5f
#define NSHARD 16

typedef unsigned short ushort_t;
typedef unsigned int uint_t;

// fp32 -> bf16 round-to-nearest-even (values are normal; no NaN handling needed)
__device__ __forceinline__ ushort_t f2bf(float f) {
    uint_t u = __float_as_uint(f);
    uint_t r = (u + 0x7FFFu + ((u >> 16) & 1u)) >> 16;
    return (ushort_t)r;
}

// unpack 8 bf16 (one uint4) -> 8 fp32
__device__ __forceinline__ void bf8_to_f32(const uint4 v, float f[8]) {
    f[0] = __uint_as_float(v.x << 16);
    f[1] = __uint_as_float(v.x & 0xFFFF0000u);
    f[2] = __uint_as_float(v.y << 16);
    f[3] = __uint_as_float(v.y & 0xFFFF0000u);
    f[4] = __uint_as_float(v.z << 16);
    f[5] = __uint_as_float(v.z & 0xFFFF0000u);
    f[6] = __uint_as_float(v.w << 16);
    f[7] = __uint_as_float(v.w & 0xFFFF0000u);
}

// ---------------- CSR build ----------------

__global__ void k_hist(const int* __restrict__ ei, int* __restrict__ cntS,
                       int* __restrict__ rank) {
    int e = blockIdx.x * blockDim.x + threadIdx.x;
    if (e < N_EDGES) {
        int d = ei[N_EDGES + e];
        int s = blockIdx.x & (NSHARD - 1);
        rank[e] = atomicAdd(&cntS[s * N_NODES + d], 1);
    }
}

__global__ void k_sumsh(int* __restrict__ cntS, int* __restrict__ cnt) {
    int i = blockIdx.x * blockDim.x + threadIdx.x;
    if (i < N_NODES) {
        int run = 0;
#pragma unroll
        for (int s = 0; s < NSHARD; s++) {
            int c = cntS[s * N_NODES + i];
            cntS[s * N_NODES + i] = run;
            run += c;
        }
        cnt[i] = run;
    }
}

__global__ void k_scan1(const int* __restrict__ cnt, int* __restrict__ exc,
                        int* __restrict__ bsums) {
    __shared__ int s[256];
    int i = blockIdx.x * 256 + threadIdx.x;
    int v = (i < N_NODES) ? cnt[i] : 0;
    s[threadIdx.x] = v;
    __syncthreads();
    for (int off = 1; off < 256; off <<= 1) {
        int t = (threadIdx.x >= off) ? s[threadIdx.x - off] : 0;
        __syncthreads();
        s[threadIdx.x] += t;
        __syncthreads();
    }
    if (i < N_NODES) exc[i] = s[threadIdx.x] - v;
    if (threadIdx.x == 255) bsums[blockIdx.x] = s[255];
}

__global__ void k_scan2(const int* __restrict__ bsums, int* __restrict__ boffs, int nb) {
    __shared__ int s[512];
    int v = ((int)threadIdx.x < nb) ? bsums[threadIdx.x] : 0;
    s[threadIdx.x] = v;
    __syncthreads();
    for (int off = 1; off < 512; off <<= 1) {
        int t = (threadIdx.x >= off) ? s[threadIdx.x - off] : 0;
        __syncthreads();
        s[threadIdx.x] += t;
        __syncthreads();
    }
    if ((int)threadIdx.x < nb) boffs[threadIdx.x] = s[threadIdx.x] - v;
}

__global__ void k_scan3(int* __restrict__ exc, const int* __restrict__ boffs) {
    int i = blockIdx.x * 256 + threadIdx.x;
    if (i < N_NODES) exc[i] += boffs[blockIdx.x];
}

__global__ void k_fill(const int* __restrict__ ei, const int* __restrict__ rowptr,
                       const int* __restrict__ cntS, const int* __restrict__ rank,
                       int* __restrict__ csr) {
    int e = blockIdx.x * blockDim.x + threadIdx.x;
    if (e < N_EDGES) {
        int d = ei[N_EDGES + e];
        int s = blockIdx.x & (NSHARD - 1);
        csr[rowptr[d] + cntS[s * N_NODES + d] + rank[e]] = ei[e];
    }
}

__global__ void k_prep(const int* __restrict__ cnt, const int* __restrict__ batch,
                       float* __restrict__ invdeg, float* __restrict__ invg) {
    int i = blockIdx.x * blockDim.x + threadIdx.x;
    if (i < N_NODES) invdeg[i] = 1.0f / (float)max(cnt[i], 1);
    if (i < NGRAPH) {
        int key = i, lo = 0, hi = N_NODES;
        while (lo < hi) { int m = (lo + hi) >> 1; if (batch[m] < key) lo = m + 1; else hi = m; }
        int a = lo;
        key = i + 1; lo = 0; hi = N_NODES;
        while (lo < hi) { int m = (lo + hi) >> 1; if (batch[m] < key) lo = m + 1; else hi = m; }
        invg[i] = 1.0f / (float)max(lo - a, 1);
    }
}

// x (fp32) -> bf16 copy for the layer-0 gather target
__global__ void k_xcast(const float* __restrict__ x, ushort_t* __restrict__ xh) {
    int i = blockIdx.x * blockDim.x + threadIdx.x;  // one float4 per thread
    if (i < N_NODES * 16) {
        const float4 v = ((const float4*)x)[i];
        ushort4 u;
        u.x = f2bf(v.x); u.y = f2bf(v.y); u.z = f2bf(v.z); u.w = f2bf(v.w);
        ((ushort4*)xh)[i] = u;
    }
}

// One masked group of 8 edges; bf16 rows, 8-lane row layout:
// lane = (q,r): q=lane>>3 edge slot (0..7), r=lane&7 column octet (8 bf16 = 16B).
// 1 idx load + 1 dwordx4 gather covers 8 edges per wave-instruction (1 KB).
__device__ __forceinline__ void grp8b(const ushort_t* __restrict__ h,
                                      const int* __restrict__ cp,
                                      int e, int deg, int q, int r,
                                      float acc[8]) {
    const int last = deg - 1;
    const int e0 = e + q;
    int i0 = cp[min(e0, last)];
    float m0 = (e0 < deg) ? 1.f : 0.f;
    const uint4 v = *(const uint4*)(h + (size_t)i0 * 64 + r * 8);
    float f[8];
    bf8_to_f32(v, f);
#pragma unroll
    for (int j = 0; j < 8; j++) acc[j] = fmaf(f[j], m0, acc[j]);
}

// ---------------- Layer pass A: aggregate + GEMV(W1) + BN moments ----------------
// bf16 gather target halves L2-miss bytes (the r6 bottleneck: 187 MB misses at
// ~2.4 TB/s). GEMV stays fp32 with W1 column register-resident.

#define CHUNK_A 14  // even: pair loop covers every wave's range exactly

__global__ __launch_bounds__(256, 4)
void k_passA(const ushort_t* __restrict__ h, const float* __restrict__ W1,
             const float* __restrict__ b1,
             const int* __restrict__ rowptr, const int* __restrict__ cnt,
             const int* __restrict__ csr, const float* __restrict__ invdeg,
             float* __restrict__ z, float* __restrict__ colsum,
             float* __restrict__ colsumsq) {
    const int lane = threadIdx.x & 63;
    const int q = lane >> 3;
    const int r = lane & 7;
    int wid_raw = (blockIdx.x << 2) | (threadIdx.x >> 6);
    const int wid = __builtin_amdgcn_readfirstlane(wid_raw);
    const int n0 = wid * CHUNK_A;
    const int n1 = min(N_NODES, n0 + CHUNK_A);

    float w[64];
#pragma unroll
    for (int k = 0; k < 64; k++) w[k] = W1[k * 64 + lane];
#pragma unroll
    for (int k = 0; k < 64; k++) asm("" : "+v"(w[k]));   // keep register-resident
    const float bj = b1[lane];

    float ls = 0.f, lq = 0.f;
    for (int n = n0; n + 2 <= n1; n += 2) {
        const int sa = rowptr[n],     da = cnt[n];
        const int sb = rowptr[n + 1], db = cnt[n + 1];
        const float idga = invdeg[n], idgb = invdeg[n + 1];
        const int* __restrict__ ca = csr + sa;
        const int* __restrict__ cb = csr + sb;

        float aa[8] = {0,0,0,0,0,0,0,0};
        float ab[8] = {0,0,0,0,0,0,0,0};
        const int m = min(da, db);
        int e = 0;
        for (; e < m; e += 8) {            // dual independent gather streams
            grp8b(h, ca, e, da, q, r, aa);
            grp8b(h, cb, e, db, q, r, ab);
        }
        for (; e < da; e += 8) grp8b(h, ca, e, da, q, r, aa);
        for (; e < db; e += 8) grp8b(h, cb, e, db, q, r, ab);

        // reduce the 8 edge-slot partials (lane bits 3,4,5)
#pragma unroll
        for (int j = 0; j < 8; j++) {
            aa[j] += __shfl_xor(aa[j], 8, 64);
            aa[j] += __shfl_xor(aa[j], 16, 64);
            aa[j] += __shfl_xor(aa[j], 32, 64);
            ab[j] += __shfl_xor(ab[j], 8, 64);
            ab[j] += __shfl_xor(ab[j], 16, 64);
            ab[j] += __shfl_xor(ab[j], 32, 64);
        }

        // self rows (all lanes redundantly hold their column-octet)
        const uint4 sva = *(const uint4*)(h + (size_t)n * 64 + r * 8);
        const uint4 svb = *(const uint4*)(h + (size_t)(n + 1) * 64 + r * 8);
        float sa8[8], sb8[8];
        bf8_to_f32(sva, sa8);
        bf8_to_f32(svb, sb8);
        float ta[8], tb[8];
#pragma unroll
        for (int j = 0; j < 8; j++) {
            ta[j] = fmaf(aa[j], idga, sa8[j]);
            tb[j] = fmaf(ab[j], idgb, sb8[j]);
        }

        // GEMV: t[k], k = rr*8+j, lives in lane rr, reg j; dual FMA chains
        float za = bj, zb = bj;
#pragma unroll
        for (int rr = 0; rr < 8; rr++) {
#pragma unroll
            for (int j = 0; j < 8; j++) {
                float ka = __int_as_float(__builtin_amdgcn_readlane(__float_as_int(ta[j]), rr));
                float kb = __int_as_float(__builtin_amdgcn_readlane(__float_as_int(tb[j]), rr));
                za = fmaf(ka, w[rr * 8 + j], za);
                zb = fmaf(kb, w[rr * 8 + j], zb);
            }
        }
        z[(size_t)n * 64 + lane] = za;
        z[(size_t)(n + 1) * 64 + lane] = zb;
        ls += za + zb;
        lq += za * za + zb * zb;
    }

    __shared__ float rs[256], rq[256];
    rs[threadIdx.x] = ls;
    rq[threadIdx.x] = lq;
    __syncthreads();
    if (threadIdx.x < 64) {
        float a = rs[threadIdx.x] + rs[threadIdx.x + 64] + rs[threadIdx.x + 128] + rs[threadIdx.x + 192];
        float b = rq[threadIdx.x] + rq[threadIdx.x + 64] + rq[threadIdx.x + 128] + rq[threadIdx.x + 192];
        atomicAdd(&colsum[threadIdx.x], a);
        atomicAdd(&colsumsq[threadIdx.x], b);
    }
}

// ---------------- BN prep ----------------

__global__ void k_bnprep(float* __restrict__ colsum, float* __restrict__ colsumsq,
                         const float* __restrict__ gamma, const float* __restrict__ beta,
                         float* __restrict__ scale, float* __restrict__ shift) {
    int j = threadIdx.x;  // 64 threads
    float invn = 1.0f / (float)N_NODES;
    float mu = colsum[j] * invn;
    float var = colsumsq[j] * invn - mu * mu;
    float rsg = rsqrtf(var + BN_EPS);
    float sc = gamma[j] * rsg;
    scale[j] = sc;
    shift[j] = beta[j] - mu * sc;
    colsum[j] = 0.f;
    colsumsq[j] = 0.f;
}

// ---------------- Layer pass B: BN + ReLU + GEMV(W2) + pools ----------------
// hout written as bf16 (next layer's gather target); pools stay fp32.

#define CHUNK_M 28  // multiple of 4

__global__ __launch_bounds__(256, 4)
void k_passB(const float* __restrict__ z, const float* __restrict__ W2,
             const float* __restrict__ b2, const float* __restrict__ scale,
             const float* __restrict__ shift, const int* __restrict__ batch,
             ushort_t* __restrict__ hout, float* __restrict__ node_pool,
             float* __restrict__ gacc, int first) {
    const int lane = threadIdx.x & 63;
    int wid_raw = (blockIdx.x << 2) | (threadIdx.x >> 6);
    const int wid = __builtin_amdgcn_readfirstlane(wid_raw);
    const int n0 = wid * CHUNK_M;
    const int n1 = min(N_NODES, n0 + CHUNK_M);

    float w[64];
#pragma unroll
    for (int k = 0; k < 64; k++) w[k] = W2[k * 64 + lane];
#pragma unroll
    for (int k = 0; k < 64; k++) asm("" : "+v"(w[k]));
    const float bj = b2[lane], sc = scale[lane], sh = shift[lane];

    int curg = -1;
    float ga = 0.f;
    for (int n = n0; n + 4 <= n1; n += 4) {
        float ra = fmaxf(fmaf(z[(size_t)n * 64 + lane], sc, sh), 0.f);
        float rb = fmaxf(fmaf(z[(size_t)(n + 1) * 64 + lane], sc, sh), 0.f);
        float rc = fmaxf(fmaf(z[(size_t)(n + 2) * 64 + lane], sc, sh), 0.f);
        float rd = fmaxf(fmaf(z[(size_t)(n + 3) * 64 + lane], sc, sh), 0.f);
        float ha = bj, hb = bj, hc = bj, hd = bj;
#pragma unroll
        for (int k = 0; k < 64; k++) {
            float ka = __int_as_float(__builtin_amdgcn_readlane(__float_as_int(ra), k));
            float kb = __int_as_float(__builtin_amdgcn_readlane(__float_as_int(rb), k));
            float kc = __int_as_float(__builtin_amdgcn_readlane(__float_as_int(rc), k));
            float kd = __int_as_float(__builtin_amdgcn_readlane(__float_as_int(rd), k));
            ha = fmaf(ka, w[k], ha);
            hb = fmaf(kb, w[k], hb);
            hc = fmaf(kc, w[k], hc);
            hd = fmaf(kd, w[k], hd);
        }
        hout[(size_t)n * 64 + lane] = f2bf(ha);
        hout[(size_t)(n + 1) * 64 + lane] = f2bf(hb);
        hout[(size_t)(n + 2) * 64 + lane] = f2bf(hc);
        hout[(size_t)(n + 3) * 64 + lane] = f2bf(hd);
        if (first) {
            node_pool[(size_t)n * 64 + lane] = ha;
            node_pool[(size_t)(n + 1) * 64 + lane] = hb;
            node_pool[(size_t)(n + 2) * 64 + lane] = hc;
            node_pool[(size_t)(n + 3) * 64 + lane] = hd;
        } else {
            node_pool[(size_t)n * 64 + lane] += ha;
            node_pool[(size_t)(n + 1) * 64 + lane] += hb;
            node_pool[(size_t)(n + 2) * 64 + lane] += hc;
            node_pool[(size_t)(n + 3) * 64 + lane] += hd;
        }
        float hv[4] = {ha, hb, hc, hd};
#pragma unroll
        for (int j = 0; j < 4; j++) {
            int g = batch[n + j];
            if (g != curg) {
                if (curg >= 0) atomicAdd(&gacc[curg * 64 + lane], ga);
                ga = 0.f;
                curg = g;
            }
            ga += hv[j];
        }
    }
    if (curg >= 0) atomicAdd(&gacc[curg * 64 + lane], ga);
}

__global__ void k_gfinal(const float* __restrict__ gacc, const float* __restrict__ invg,
                         float* __restrict__ gout) {
    int i = blockIdx.x * blockDim.x + threadIdx.x;
    if (i < NGRAPH * 64) gout[i] = gacc[i] * invg[i >> 6];
}

// ---------------- launch ----------------

extern "C" void kernel_launch(void* const* d_in, const int* in_sizes, int n_in,
                              void* d_out, int out_size, void* d_ws, size_t ws_size,
                              hipStream_t stream) {
    (void)in_sizes; (void)n_in; (void)out_size; (void)ws_size;
    const float* x     = (const float*)d_in[0];
    const int*   ei    = (const int*)d_in[1];
    const int*   batch = (const int*)d_in[2];
    const float* W1    = (const float*)d_in[3];
    const float* b1    = (const float*)d_in[4];
    const float* gamma = (const float*)d_in[5];
    const float* beta  = (const float*)d_in[6];
    const float* W2    = (const float*)d_in[7];
    const float* b2    = (const float*)d_in[8];
    float* out = (float*)d_out;  // [N*64] node_pool, then [G*64] g_pool

    // element offsets (4B units); all kept multiple of 4 for 16B alignment
    size_t o = 0;
    size_t o_cntS    = o; o += (size_t)NSHARD * N_NODES;
    size_t o_colsum  = o; o += 64;
    size_t o_colsq   = o; o += 64;
    size_t o_gacc    = o; o += (size_t)NGRAPH * 64;
    size_t zero_elems = o;
    size_t o_cnt     = o; o += N_NODES;
    size_t o_rowptr  = o; o += N_NODES;
    size_t o_bsums   = o; o += 512;
    size_t o_boffs   = o; o += 512;
    size_t o_invdeg  = o; o += N_NODES;
    size_t o_invg    = o; o += NGRAPH;
    size_t o_scale   = o; o += 64;
    size_t o_shift   = o; o += 64;
    size_t o_rank    = o; o += N_EDGES;
    size_t o_csr     = o; o += N_EDGES;
    size_t o_bufA    = o; o += (size_t)N_NODES * 64;   // z, fp32
    size_t o_bufB    = o; o += (size_t)N_NODES * 16;   // h,  bf16 (N*64 ushorts)
    size_t o_xh      = o; o += (size_t)N_NODES * 16;   // x,  bf16

    int*   wsi = (int*)d_ws;
    float* wsf = (float*)d_ws;
    int*      cntS   = wsi + o_cntS;
    float*    colsum = wsf + o_colsum;
    float*    colsq  = wsf + o_colsq;
    float*    gacc   = wsf + o_gacc;
    int*      cnt    = wsi + o_cnt;
    int*      rowptr = wsi + o_rowptr;
    int*      bsums  = wsi + o_bsums;
    int*      boffs  = wsi + o_boffs;
    float*    invdeg = wsf + o_invdeg;
    float*    invg   = wsf + o_invg;
    float*    scale  = wsf + o_scale;
    float*    shift  = wsf + o_shift;
    int*      rank   = wsi + o_rank;
    int*      csr    = wsi + o_csr;
    float*    bufA   = wsf + o_bufA;
    ushort_t* bufB   = (ushort_t*)(wsi + o_bufB);
    ushort_t* xh     = (ushort_t*)(wsi + o_xh);

    hipMemsetAsync(d_ws, 0, zero_elems * 4, stream);

    const int eb = (N_EDGES + 255) / 256;
    const int nb = (N_NODES + 255) / 256;  // 391 <= 512

    k_hist<<<eb, 256, 0, stream>>>(ei, cntS, rank);
    k_xcast<<<(N_NODES * 16 + 255) / 256, 256, 0, stream>>>(x, xh);
    k_sumsh<<<nb, 256, 0, stream>>>(cntS, cnt);
    k_scan1<<<nb, 256, 0, stream>>>(cnt, rowptr, bsums);
    k_scan2<<<1, 512, 0, stream>>>(bsums, boffs, nb);
    k_scan3<<<nb, 256, 0, stream>>>(rowptr, boffs);
    k_prep<<<nb, 256, 0, stream>>>(cnt, batch, invdeg, invg);
    k_fill<<<eb, 256, 0, stream>>>(ei, rowptr, cntS, rank, csr);

    const int gridA = (N_NODES + CHUNK_A * 4 - 1) / (CHUNK_A * 4);     // 1786
    const int gridM = (N_NODES + CHUNK_M * 4 - 1) / (CHUNK_M * 4);     // 893
    for (int l = 0; l < NLAYER; l++) {
        const ushort_t* h_in = (l == 0) ? xh : bufB;
        k_passA<<<gridA, 256, 0, stream>>>(h_in, W1 + l * 4096, b1 + l * 64,
                                           rowptr, cnt, csr, invdeg,
                                           bufA, colsum, colsq);
        k_bnprep<<<1, 64, 0, stream>>>(colsum, colsq, gamma + l * 64, beta + l * 64,
                                       scale, shift);
        k_passB<<<gridM, 256, 0, stream>>>(bufA, W2 + l * 4096, b2 + l * 64,
                                           scale, shift, batch,
                                           bufB, out, gacc, (l == 0) ? 1 : 0);
    }
    k_gfinal<<<32, 256, 0, stream>>>(gacc, invg, out + (size_t)N_NODES * 64);
}